// Round 2
// baseline (1778.551 us; speedup 1.0000x reference)
//
#include <hip/hip_runtime.h>
#include <math.h>

#define BATCH 2048
#define SEQ 512
#define CH 16
#define PLEN 16
#define NP 63
#define TP 42
#define DM 128
#define PCDIM 256
#define PRUNE 64
#define HID 256
#define PRED 336

// workspace offsets (floats)
#define O_WPET2   0          // [64][128][4]   = 32768
#define O_WCMPT4  32768      // [2016][64][4]  = 516096
#define O_W1T4    548864     // [16][512][4]   = 32768
#define O_W2T4    581632     // [64][256][4]   = 65536
#define O_WD1T4   647168     // [32][256][4]   = 32768
#define O_WD2T4   679936     // [64][256][4]   = 65536
#define O_SSTATE  745472     // [2048][192]    = 393216
#define O_FEAT    1138688    // [2048][8064]   = 16515072
#define O_ZTRAJ   17653760   // [42][2048][128]= 11010048
#define WS_TOTAL  28663808

__device__ __forceinline__ float silu_f(float v){ return v / (1.0f + expf(-v)); }

// ---------------- repack: transpose weights into [k4][j][4] layouts ----------
__global__ void repack_kernel(const float* __restrict__ Wpe, const float* __restrict__ Wcmp,
                              const float* __restrict__ Wn1, const float* __restrict__ Wn2,
                              const float* __restrict__ Wl1, const float* __restrict__ Wl2,
                              const float* __restrict__ Wd1, const float* __restrict__ Wd2,
                              float* __restrict__ ws){
  const int tot = 745472;
  for (int e = blockIdx.x*blockDim.x + threadIdx.x; e < tot; e += gridDim.x*blockDim.x){
    float v; int x = e;
    if (x < 32768){                       // WpeT2 [k4][128][4]
      int kk = x & 3, d = (x>>2)&127, k4 = x>>9;
      v = Wpe[d*256 + k4*4 + kk];
    } else if ((x -= 32768) < 516096){    // WcmpT4 [2016][64][4]
      int kk = x&3, j = (x>>2)&63, k4 = x>>8;
      v = Wcmp[j*8064 + k4*4 + kk];
    } else if ((x -= 516096) < 32768){    // W1T4 [16][512][4]  (Wn1 ; Wl1)
      int kk = x&3, j = (x>>2)&511, k4 = x>>11; int k = k4*4+kk;
      v = (j < 256) ? Wn1[j*64 + k] : Wl1[(j-256)*64 + k];
    } else if ((x -= 32768) < 65536){     // W2T4 [64][256][4]  (Wn2 ; Wl2 ; pad)
      int kk = x&3, j = (x>>2)&255, k4 = x>>10; int k = k4*4+kk;
      v = (j < 64) ? Wn2[j*256 + k] : ((j < 192) ? Wl2[(j-64)*256 + k] : 0.0f);
    } else if ((x -= 65536) < 32768){     // Wd1T4 [32][256][4]
      int kk = x&3, j = (x>>2)&255, k4 = x>>10;
      v = Wd1[j*128 + k4*4 + kk];
    } else { x -= 32768;                  // Wd2T4 [64][256][4]
      int kk = x&3, j = (x>>2)&255, k4 = x>>10;
      v = Wd2[j*256 + k4*4 + kk];
    }
    ws[e] = v;
  }
}

// ---------------- K1: patch-embed GEMM + depthwise conv + silu + z0 ----------
// one block per batch element
__global__ __launch_bounds__(256) void k1_embed(const float* __restrict__ x,
        const float* __restrict__ ws, const float* __restrict__ b_pe,
        const float* __restrict__ Wconv, const float* __restrict__ b_conv,
        float* __restrict__ feat, float* __restrict__ sstate){
  __shared__ __align__(16) float xT[16*512];     // [c][l]
  __shared__ float pe_s[63*132];                 // [p][d] stride 132 (pad)
  const float* __restrict__ WpeT2 = ws + O_WPET2;
  const int b = blockIdx.x;
  const int t = threadIdx.x;
  const float* xb = x + (size_t)b*(SEQ*CH);
  // stage x transposed
  for (int rep = 0; rep < 2; ++rep){
    int l = t + rep*256;
    const float* src = xb + l*16;
    #pragma unroll
    for (int c4 = 0; c4 < 4; ++c4){
      float4 v = *(const float4*)(src + c4*4);
      xT[(c4*4+0)*512 + l] = v.x;
      xT[(c4*4+1)*512 + l] = v.y;
      xT[(c4*4+2)*512 + l] = v.z;
      xT[(c4*4+3)*512 + l] = v.w;
    }
  }
  __syncthreads();
  // pe GEMM: thread tile = 8 d (strided 16) x 4 p
  const int dgrp = t & 15;
  const int p0 = (t >> 4) * 4;
  float acc[8][4];
  #pragma unroll
  for (int j = 0; j < 8; ++j)
    #pragma unroll
    for (int pi = 0; pi < 4; ++pi) acc[j][pi] = 0.0f;
  for (int c = 0; c < 16; ++c){
    #pragma unroll
    for (int t4 = 0; t4 < 4; ++t4){
      const int k4 = c*4 + t4;
      float4 xv[4];
      #pragma unroll
      for (int pi = 0; pi < 4; ++pi){
        int p = p0 + pi; int pr = (p < 63) ? p : 62;
        xv[pi] = *(const float4*)(&xT[c*512 + pr*8 + t4*4]);
      }
      #pragma unroll
      for (int j = 0; j < 8; ++j){
        float4 wv = *(const float4*)(&WpeT2[(k4*128 + j*16 + dgrp)*4]);
        #pragma unroll
        for (int pi = 0; pi < 4; ++pi){
          acc[j][pi] += wv.x*xv[pi].x + wv.y*xv[pi].y + wv.z*xv[pi].z + wv.w*xv[pi].w;
        }
      }
    }
  }
  #pragma unroll
  for (int j = 0; j < 8; ++j){
    int d = j*16 + dgrp;
    float bp = b_pe[d];
    #pragma unroll
    for (int pi = 0; pi < 4; ++pi){
      int p = p0 + pi;
      if (p < 63) pe_s[p*132 + d] = acc[j][pi] + bp;
    }
  }
  __syncthreads();
  // conv (left-pad 2) + silu -> feat ; z0 = pe[62]
  const int d = t & 127;
  const int ph = t >> 7;
  float w0 = Wconv[d*3+0], w1 = Wconv[d*3+1], w2 = Wconv[d*3+2];
  float bc = b_conv[d];
  float* featb = feat + (size_t)b*(NP*DM);
  for (int q = 0; q < 32; ++q){
    int p = ph*32 + q;
    if (p < 63){
      float s = bc + w2*pe_s[p*132+d];
      if (p >= 1) s += w1*pe_s[(p-1)*132+d];
      if (p >= 2) s += w0*pe_s[(p-2)*132+d];
      featb[p*128 + d] = silu_f(s);
    }
  }
  if (ph == 0){
    sstate[(size_t)b*192 + 64 + d] = pe_s[62*132 + d];
  }
}

// ---------------- K2: a0 = feat_flat @ Wcmp^T + b_cmp -----------------------
// 256 blocks x 256 threads, 8 batch rows per block
__global__ __launch_bounds__(256) void k2_cmp(const float* __restrict__ feat,
      const float* __restrict__ ws, const float* __restrict__ b_cmp,
      float* __restrict__ sstate){
  const float* __restrict__ WcmpT4 = ws + O_WCMPT4;
  __shared__ __align__(16) float fs[8*512];
  const int b0 = blockIdx.x * 8;
  const int t = threadIdx.x;
  const int j = t & 63, bq = t >> 6;
  float acc0 = 0.0f, acc1 = 0.0f;
  for (int chk = 0; chk < 16; ++chk){
    const int k0 = chk*512;
    const int lim = (8064 - k0 < 512) ? (8064 - k0) : 512;
    __syncthreads();
    for (int u = 0; u < 16; ++u){
      int idx = u*256 + t;
      int bb = idx >> 9, kk = idx & 511;
      fs[idx] = (kk < lim) ? feat[(size_t)(b0+bb)*8064 + k0 + kk] : 0.0f;
    }
    __syncthreads();
    const int nk4 = lim >> 2;
    const float* wbase = &WcmpT4[(k0>>2)*256 + j*4];
    const float* f0 = &fs[(bq*2+0)*512];
    const float* f1 = &fs[(bq*2+1)*512];
    for (int k4 = 0; k4 < nk4; ++k4){
      float4 wv = *(const float4*)(wbase + k4*256);
      float4 a0 = *(const float4*)(f0 + k4*4);
      float4 a1 = *(const float4*)(f1 + k4*4);
      acc0 += wv.x*a0.x + wv.y*a0.y + wv.z*a0.z + wv.w*a0.w;
      acc1 += wv.x*a1.x + wv.y*a1.y + wv.z*a1.z + wv.w*a1.w;
    }
  }
  float bj = b_cmp[j];
  sstate[(size_t)(b0 + bq*2 + 0)*192 + j] = acc0 + bj;
  sstate[(size_t)(b0 + bq*2 + 1)*192 + j] = acc1 + bj;
}

// ---------------- K3: 42-step Euler ODE, per-row-resident -------------------
// 256 blocks x 512 threads, 8 rows per block
__global__ __launch_bounds__(512) void k3_ode(const float* __restrict__ ws,
      const float* __restrict__ b_n1, const float* __restrict__ b_l1,
      const float* __restrict__ b_n2, const float* __restrict__ b_l2,
      const float* __restrict__ spanA,
      float* __restrict__ sstate, float* __restrict__ ztraj){
  const float* __restrict__ W1T4 = ws + O_W1T4;
  const float* __restrict__ W2T4 = ws + O_W2T4;
  __shared__ __align__(16) float a_s[8*64];
  __shared__ __align__(16) float h_s[8*512];
  __shared__ __align__(16) float c_s[8*128];
  __shared__ __align__(16) float zd[8*260];       // z duplicated [i]&[i+128]
  __shared__ float part2[2*8*256];
  __shared__ __align__(16) float dzp[2*8*128];
  const int t = threadIdx.x;
  const int b0 = blockIdx.x * 8;
  const float dt = fminf(fmaxf(spanA[0], 1e-8f), 5.0f);
  // load state
  {
    int r = t >> 6, jj = t & 63;
    a_s[t] = sstate[(size_t)(b0+r)*192 + jj];
    for (int u = 0; u < 2; ++u){
      int idx = u*512 + t; int rr = idx >> 7, i = idx & 127;
      float zv = sstate[(size_t)(b0+rr)*192 + 64 + i];
      zd[rr*260 + i] = zv; zd[rr*260 + 128 + i] = zv;
    }
  }
  const float b1 = (t < 256) ? b_n1[t] : b_l1[t-256];
  const int j2 = t & 255;
  const int rb = t >> 8;
  const float bias2 = (j2 < 64) ? b_n2[j2] : ((j2 < 192) ? b_l2[j2-64] : 0.0f);
  __syncthreads();

  for (int st = 0; st < TP; ++st){
    // P0: h = silu(W1 @ a + b1), 512 outputs x 8 rows
    {
      float acc[8];
      #pragma unroll
      for (int r = 0; r < 8; ++r) acc[r] = 0.0f;
      for (int k4 = 0; k4 < 16; ++k4){
        float4 wv = *(const float4*)(&W1T4[(k4*512 + t)*4]);
        #pragma unroll
        for (int r = 0; r < 8; ++r){
          float4 av = *(const float4*)(&a_s[r*64 + k4*4]);
          acc[r] += wv.x*av.x + wv.y*av.y + wv.z*av.z + wv.w*av.w;
        }
      }
      #pragma unroll
      for (int r = 0; r < 8; ++r) h_s[r*512 + t] = silu_f(acc[r] + b1);
    }
    __syncthreads();
    // P1: partial GEMV2 (da:64, c:128 outputs), split k into halves
    {
      const int kh = t >> 8;
      if (j2 < 192){
        float acc[8];
        #pragma unroll
        for (int r = 0; r < 8; ++r) acc[r] = 0.0f;
        const int hoff = (j2 < 64) ? 0 : 256;
        for (int k4i = 0; k4i < 32; ++k4i){
          const int k4 = kh*32 + k4i;
          float4 wv = *(const float4*)(&W2T4[(k4*256 + j2)*4]);
          #pragma unroll
          for (int r = 0; r < 8; ++r){
            float4 hv = *(const float4*)(&h_s[r*512 + hoff + k4*4]);
            acc[r] += wv.x*hv.x + wv.y*hv.y + wv.z*hv.z + wv.w*hv.w;
          }
        }
        #pragma unroll
        for (int r = 0; r < 8; ++r) part2[(kh*8 + r)*256 + j2] = acc[r];
      }
    }
    __syncthreads();
    // P2: combine + tanh; update a, write c
    if (j2 < 192){
      #pragma unroll
      for (int u = 0; u < 4; ++u){
        int r = u*2 + rb;
        float v = part2[r*256 + j2] + part2[(8+r)*256 + j2] + bias2;
        float tv = tanhf(v);
        if (j2 < 64) a_s[r*64 + j2] += dt * tv;
        else         c_s[r*128 + (j2-64)] = tv;
      }
    }
    __syncthreads();
    // P3: dz partials: dz[i] = sum_m c[m] * z[(i+m)&127]
    {
      const int i0 = (t & 31) * 4;
      const int r  = (t >> 5) & 7;
      const int mh = t >> 8;
      const int mbase = mh * 64;
      float m0=0.f, m1=0.f, m2=0.f, m3=0.f;
      const float* zr = &zd[r*260];
      const float* cr = &c_s[r*128];
      for (int mc = 0; mc < 16; ++mc){
        const int m = mbase + mc*4;
        float4 cv = *(const float4*)(cr + m);
        float4 za = *(const float4*)(zr + i0 + m);
        float4 zb = *(const float4*)(zr + i0 + m + 4);
        m0 += cv.x*za.x + cv.y*za.y + cv.z*za.z + cv.w*za.w;
        m1 += cv.x*za.y + cv.y*za.z + cv.z*za.w + cv.w*zb.x;
        m2 += cv.x*za.z + cv.y*za.w + cv.z*zb.x + cv.w*zb.y;
        m3 += cv.x*za.w + cv.y*zb.x + cv.z*zb.y + cv.w*zb.z;
      }
      *(float4*)(&dzp[(mh*8 + r)*128 + i0]) = make_float4(m0, m1, m2, m3);
    }
    __syncthreads();
    // P4: z update + store to ztraj
    {
      float* zt = ztraj + (size_t)st*(BATCH*DM);
      for (int u = 0; u < 2; ++u){
        int idx = u*512 + t; int r = idx >> 7, i = idx & 127;
        float dz = dzp[r*128 + i] + dzp[(8+r)*128 + i];
        float zn = zd[r*260 + i] + dt*dz;
        zd[r*260 + i] = zn; zd[r*260 + 128 + i] = zn;
        zt[(size_t)(b0+r)*128 + i] = zn;
      }
    }
    __syncthreads();
  }
}

// ---------------- K4: decoder + fused overlap-add (atomics) -----------------
// 32 rows (st,b) per block
__global__ __launch_bounds__(256) void k4_dec(const float* __restrict__ ztraj,
    const float* __restrict__ ws, const float* __restrict__ b_d1,
    const float* __restrict__ b_d2, float* __restrict__ xpred){
  const float* __restrict__ Wd1T4 = ws + O_WD1T4;
  const float* __restrict__ Wd2T4 = ws + O_WD2T4;
  __shared__ __align__(16) float z_s[32*128];
  __shared__ __align__(16) float h_sh[32*256];
  const int t = threadIdx.x;
  const int m0 = blockIdx.x * 32;
  // stage z rows
  for (int u = 0; u < 4; ++u){
    int idx4 = u*256 + t;
    ((float4*)z_s)[idx4] = *(const float4*)(ztraj + (size_t)m0*128 + idx4*4);
  }
  __syncthreads();
  float acc[32];
  #pragma unroll
  for (int r = 0; r < 32; ++r) acc[r] = 0.0f;
  for (int k4 = 0; k4 < 32; ++k4){
    float4 wv = *(const float4*)(&Wd1T4[(k4*256 + t)*4]);
    #pragma unroll
    for (int r = 0; r < 32; ++r){
      float4 zv = *(const float4*)(&z_s[r*128 + k4*4]);
      acc[r] += wv.x*zv.x + wv.y*zv.y + wv.z*zv.z + wv.w*zv.w;
    }
  }
  {
    float bd1 = b_d1[t];
    #pragma unroll
    for (int r = 0; r < 32; ++r) h_sh[r*256 + t] = silu_f(acc[r] + bd1);
  }
  __syncthreads();
  #pragma unroll
  for (int r = 0; r < 32; ++r) acc[r] = 0.0f;
  for (int k4 = 0; k4 < 64; ++k4){
    float4 wv = *(const float4*)(&Wd2T4[(k4*256 + t)*4]);
    #pragma unroll
    for (int r = 0; r < 32; ++r){
      float4 hv = *(const float4*)(&h_sh[r*256 + k4*4]);
      acc[r] += wv.x*hv.x + wv.y*hv.y + wv.z*hv.z + wv.w*hv.w;
    }
  }
  const float bd2 = b_d2[t];
  const int tt_ = t >> 4, cc = t & 15;
  #pragma unroll
  for (int r = 0; r < 32; ++r){
    int m = m0 + r;
    int st = m >> 11;
    int b  = m & 2047;
    int tau = st*8 + tt_;
    if (tau < PRED){
      float scale = 1.0f / (((tau < 8) ? 1.0f : 2.0f) + 1e-6f);
      atomicAdd(&xpred[(size_t)b*(PRED*CH) + tau*16 + cc], (acc[r] + bd2) * scale);
    }
  }
}

// ---------------- launch ----------------------------------------------------
extern "C" void kernel_launch(void* const* d_in, const int* in_sizes, int n_in,
                              void* d_out, int out_size, void* d_ws, size_t ws_size,
                              hipStream_t stream){
  const float* x    = (const float*)d_in[0];
  const float* Wpe  = (const float*)d_in[1];
  const float* bpe  = (const float*)d_in[2];
  const float* Wconv= (const float*)d_in[3];
  const float* bconv= (const float*)d_in[4];
  const float* Wcmp = (const float*)d_in[5];
  const float* bcmp = (const float*)d_in[6];
  const float* Wn1  = (const float*)d_in[7];
  const float* bn1  = (const float*)d_in[8];
  const float* Wn2  = (const float*)d_in[9];
  const float* bn2  = (const float*)d_in[10];
  const float* Wl1  = (const float*)d_in[11];
  const float* bl1  = (const float*)d_in[12];
  const float* Wl2  = (const float*)d_in[13];
  const float* bl2  = (const float*)d_in[14];
  const float* span = (const float*)d_in[15];
  const float* Wd1  = (const float*)d_in[16];
  const float* bd1  = (const float*)d_in[17];
  const float* Wd2  = (const float*)d_in[18];
  const float* bd2  = (const float*)d_in[19];
  float* out = (float*)d_out;
  float* ws  = (float*)d_ws;

  const size_t XN  = (size_t)BATCH*SEQ*CH;     // 16777216
  const size_t XPN = (size_t)BATCH*PRED*CH;    // 11010048

  hipMemcpyAsync(out, x, XN*sizeof(float), hipMemcpyDeviceToDevice, stream);
  hipMemsetAsync(out + XN, 0, XPN*sizeof(float), stream);

  float* sstate = ws + O_SSTATE;
  float* feat   = ws + O_FEAT;
  float* ztraj  = ws + O_ZTRAJ;

  repack_kernel<<<256, 256, 0, stream>>>(Wpe, Wcmp, Wn1, Wn2, Wl1, Wl2, Wd1, Wd2, ws);
  k1_embed<<<BATCH, 256, 0, stream>>>(x, ws, bpe, Wconv, bconv, feat, sstate);
  k2_cmp<<<BATCH/8, 256, 0, stream>>>(feat, ws, bcmp, sstate);
  k3_ode<<<BATCH/8, 512, 0, stream>>>(ws, bn1, bl1, bn2, bl2, span, sstate, ztraj);
  k4_dec<<<(TP*BATCH)/32, 256, 0, stream>>>(ztraj, ws, bd1, bd2, out + XN);
}